// Round 3
// baseline (3052.360 us; speedup 1.0000x reference)
//
#include <hip/hip_runtime.h>

typedef unsigned short u16;
typedef __attribute__((ext_vector_type(8))) short short8;
typedef __attribute__((ext_vector_type(4))) float float4v;

typedef __attribute__((address_space(3))) unsigned int lds_u32;
typedef __attribute__((address_space(1))) unsigned int glb_u32;

__device__ __forceinline__ void gld16(const void* g, void* l) {
    __builtin_amdgcn_global_load_lds((const glb_u32*)g, (lds_u32*)l, 16, 0, 0);
}

__device__ __forceinline__ u16 f2bf(float f) {
    union { float f; unsigned u; } x;
    x.f = f;
    unsigned r = x.u + 0x7FFFu + ((x.u >> 16) & 1u);
    return (u16)(r >> 16);
}

// monotone u16 key of a similarity in [-1,1]; step 3.05e-5 (< bf16 screen noise)
__device__ __forceinline__ u16 simkey(float v) {
    int k = (int)((v + 1.0f) * 32768.0f);
    k = k < 0 ? 0 : (k > 65535 ? 65535 : k);
    return (u16)k;
}

// ---------------------------------------------------------------------------
// Per-row L2 norm + normalized bf16 cast (emb). One block / row, D=2048.
// ---------------------------------------------------------------------------
__global__ __launch_bounds__(256)
void rownorm_cast(const float* __restrict__ src, u16* __restrict__ dst,
                  double* __restrict__ invn)
{
    constexpr int D = 2048;
    __shared__ double red[256];
    __shared__ double invs;
    const int row = blockIdx.x;
    const int t = threadIdx.x;
    const float* sr = src + (size_t)row * D;
    float x[8];
    double ss = 0.0;
#pragma unroll
    for (int i = 0; i < 8; ++i) {
        x[i] = sr[t + i * 256];
        ss += (double)x[i] * (double)x[i];
    }
    red[t] = ss;
    __syncthreads();
    for (int s = 128; s > 0; s >>= 1) {
        if (t < s) red[t] += red[t + s];
        __syncthreads();
    }
    if (t == 0) {
        double n = sqrt(red[0]);
        double inv = 1.0 / fmax(n, 1e-12);
        invs = inv;
        invn[row] = inv;
    }
    __syncthreads();
    float inv = (float)invs;
    u16* dr = dst + (size_t)row * D;
#pragma unroll
    for (int i = 0; i < 8; ++i) dr[t + i * 256] = f2bf(x[i] * inv);
}

// ---------------------------------------------------------------------------
// Per-row L2 norm only (voc): writes double + float inverse norms.
// ---------------------------------------------------------------------------
__global__ __launch_bounds__(256)
void rownorm_only(const float* __restrict__ src, double* __restrict__ invn,
                  float* __restrict__ invnf)
{
    constexpr int D = 2048;
    __shared__ double red[256];
    const int row = blockIdx.x;
    const int t = threadIdx.x;
    const float* sr = src + (size_t)row * D;
    double ss = 0.0;
#pragma unroll
    for (int i = 0; i < 8; ++i) {
        float v = sr[t + i * 256];
        ss += (double)v * (double)v;
    }
    red[t] = ss;
    __syncthreads();
    for (int s = 128; s > 0; s >>= 1) {
        if (t < s) red[t] += red[t + s];
        __syncthreads();
    }
    if (t == 0) {
        double n = sqrt(red[0]);
        double inv = 1.0 / fmax(n, 1e-12);
        invn[row] = inv;
        invnf[row] = (float)inv;
    }
}

// ---------------------------------------------------------------------------
// Precast a block of vocab rows to normalized bf16 (chunk-local layout).
// ---------------------------------------------------------------------------
__global__ __launch_bounds__(256)
void precast_rows(const float* __restrict__ Bf, const float* __restrict__ invBf,
                  u16* __restrict__ Bbf, int colBase)
{
    const int t = threadIdx.x;
    const int v = colBase + blockIdx.x;
    float s = invBf[v];
    const float* src = Bf + (size_t)v * 2048 + t * 8;
    float4v x0 = *(const float4v*)src;
    float4v x1 = *(const float4v*)(src + 4);
    short8 pk;
    pk[0] = (short)f2bf(x0[0] * s); pk[1] = (short)f2bf(x0[1] * s);
    pk[2] = (short)f2bf(x0[2] * s); pk[3] = (short)f2bf(x0[3] * s);
    pk[4] = (short)f2bf(x1[0] * s); pk[5] = (short)f2bf(x1[1] * s);
    pk[6] = (short)f2bf(x1[2] * s); pk[7] = (short)f2bf(x1[3] * s);
    *(short8*)(Bbf + (size_t)blockIdx.x * 2048 + t * 8) = pk;
}

// ---------------------------------------------------------------------------
// GEMM (m97 structure), bf16, 128x128 tile, BK=64, 4 waves, 16x16x32 MFMA.
// Grid mapping: bx-GROUPED XCD swizzle. 768 blocks = 256 CU x 3/CU are all
// co-resident; blocks with orig%8==x land on XCD x. Give XCD x the 8x12
// rectangle bx in [8x,8x+8) x by in [0,nby): hot lines per K-step =
// (8 A-panels + 12 B-panels) x 16 KB ~ 320 KB << 4 MB L2, blocks advance K
// in lockstep -> each K-slice fetched from L3 once, L2-served to the other
// concurrent readers. Per-chunk L3 traffic ~768 MB -> ~80 MB.
// ---------------------------------------------------------------------------
__global__ __launch_bounds__(256)
void gemm_bt_u16(const u16* __restrict__ A, const u16* __restrict__ B,
                 u16* __restrict__ Csim, int ldc)
{
    constexpr int Kdim = 2048;
    __shared__ __align__(16) u16 As[128 * 64];
    __shared__ __align__(16) u16 Bs[128 * 64];
    const int tid = threadIdx.x;
    const int lane = tid & 63;
    const int wave = tid >> 6;

    // bx-grouped bijective XCD mapping (nwg = 64*nby, nwg % 8 == 0)
    const int orig = blockIdx.x;
    const int xcd = orig & 7;
    const int idx = orig >> 3;            // 0 .. 8*nby-1
    const int bx = xcd * 8 + (idx & 7);   // row tile: 8 per XCD
    const int by = idx >> 3;              // col tile: all nby per XCD
    const int rowTile = bx * 128;
    const int colTile = by * 128;

    const u16* Ab = A + (size_t)rowTile * Kdim;
    const u16* Bb = B + (size_t)colTile * Kdim;

    float4v acc[4][4];
#pragma unroll
    for (int i = 0; i < 4; ++i)
#pragma unroll
        for (int j = 0; j < 4; ++j) acc[i][j] = (float4v){0.f, 0.f, 0.f, 0.f};

    const int wm = (wave >> 1) * 64;
    const int wn = (wave & 1) * 64;
    const int lr = lane & 15;
    const int lq = lane >> 4;

    for (int k0 = 0; k0 < Kdim; k0 += 64) {
#pragma unroll
        for (int i = 0; i < 4; ++i) {
            int c = i * 256 + tid;
            int trow = c >> 3;
            int tk = (c & 7) * 8;
            gld16(Ab + (size_t)trow * Kdim + k0 + tk, &As[c * 8]);
        }
#pragma unroll
        for (int i = 0; i < 4; ++i) {
            int c = i * 256 + tid;
            int trow = c >> 3;
            int tk = (c & 7) * 8;
            gld16(Bb + (size_t)trow * Kdim + k0 + tk, &Bs[c * 8]);
        }
        __syncthreads();
#pragma unroll
        for (int ks = 0; ks < 2; ++ks) {
            short8 af[4], bfr[4];
#pragma unroll
            for (int mi = 0; mi < 4; ++mi)
                af[mi] = *(const short8*)&As[(wm + mi * 16 + lr) * 64 + ks * 32 + lq * 8];
#pragma unroll
            for (int ni = 0; ni < 4; ++ni)
                bfr[ni] = *(const short8*)&Bs[(wn + ni * 16 + lr) * 64 + ks * 32 + lq * 8];
#pragma unroll
            for (int mi = 0; mi < 4; ++mi)
#pragma unroll
                for (int ni = 0; ni < 4; ++ni)
                    acc[mi][ni] = __builtin_amdgcn_mfma_f32_16x16x32_bf16(
                        af[mi], bfr[ni], acc[mi][ni], 0, 0, 0);
        }
        __syncthreads();
    }
    // C/D layout: col = lane&15, row = (lane>>4)*4 + reg
#pragma unroll
    for (int mi = 0; mi < 4; ++mi) {
#pragma unroll
        for (int r = 0; r < 4; ++r) {
            int row = rowTile + wm + mi * 16 + lq * 4 + r;
            u16* crow = Csim + (size_t)row * ldc + colTile + wn + lr;
#pragma unroll
            for (int ni = 0; ni < 4; ++ni) crow[ni * 16] = simkey(acc[mi][ni][r]);
        }
    }
}

// ---------------------------------------------------------------------------
// Per-row top-8: one wave per row (4 rows/block, zero barriers, zero LDS).
// Packed key|idx int -> single __shfl_xor butterfly per pass. Fold: blocks
// 0..nextCols-1 also stage next chunk's bf16 B rows. grid = N/4.
// ---------------------------------------------------------------------------
__global__ __launch_bounds__(256)
void top8_merge_u16(const u16* __restrict__ sims, int cols, int colBase,
                    int* __restrict__ candK, int* __restrict__ candI, int isFirst,
                    const float* __restrict__ Bf, const float* __restrict__ invBf,
                    u16* __restrict__ Bbf, int nextBase, int nextCols)
{
    const int t = threadIdx.x;

    // fold: stage next chunk's normalized-bf16 B rows (uniform per block)
    if (blockIdx.x < nextCols) {
        int v = nextBase + blockIdx.x;
        float s = invBf[v];
        const float* src = Bf + (size_t)v * 2048 + t * 8;
        float4v x0 = *(const float4v*)src;
        float4v x1 = *(const float4v*)(src + 4);
        short8 pks;
        pks[0] = (short)f2bf(x0[0] * s); pks[1] = (short)f2bf(x0[1] * s);
        pks[2] = (short)f2bf(x0[2] * s); pks[3] = (short)f2bf(x0[3] * s);
        pks[4] = (short)f2bf(x1[0] * s); pks[5] = (short)f2bf(x1[1] * s);
        pks[6] = (short)f2bf(x1[2] * s); pks[7] = (short)f2bf(x1[3] * s);
        *(short8*)(Bbf + (size_t)blockIdx.x * 2048 + t * 8) = pks;
    }

    const int lane = t & 63;
    const int wave = t >> 6;
    const int row = blockIdx.x * 4 + wave;
    const u16* srow = sims + (size_t)row * cols;

    // load 24 keys/lane via 3 x short8 (16B aligned; OOB-of-row reads stay
    // inside the sims buffer and are masked to -1)
    int pk[24];
#pragma unroll
    for (int i = 0; i < 3; ++i) {
        short8 v = *(const short8*)(srow + i * 512 + lane * 8);
#pragma unroll
        for (int e = 0; e < 8; ++e) {
            int j = i * 512 + lane * 8 + e;
            int key = (int)(u16)v[e];
            pk[i * 8 + e] = (j < cols) ? ((key << 11) | (2047 - j)) : -1;
        }
    }

    int best[8];
#pragma unroll
    for (int p = 0; p < 8; ++p) {
        int bv = -1;
#pragma unroll
        for (int i = 0; i < 24; ++i) bv = pk[i] > bv ? pk[i] : bv;
#pragma unroll
        for (int off = 32; off > 0; off >>= 1) {
            int ov = __shfl_xor(bv, off);
            bv = ov > bv ? ov : bv;
        }
        best[p] = bv;                       // all lanes agree
        int cj = 2047 - (bv & 2047);        // winning column (chunk-local)
#pragma unroll
        for (int i = 0; i < 3; ++i)
#pragma unroll
            for (int e = 0; e < 8; ++e)
                if (i * 512 + lane * 8 + e == cj) pk[i * 8 + e] = -1;
    }

    if (lane == 0) {
        int bK[8], bI[8];
#pragma unroll
        for (int p = 0; p < 8; ++p) {
            bK[p] = best[p] >> 11;
            bI[p] = colBase + (2047 - (best[p] & 2047));
        }
        if (isFirst) {
            for (int i = 0; i < 8; ++i) {
                candK[row * 8 + i] = bK[i];
                candI[row * 8 + i] = bI[i];
            }
        } else {
            int oK[8], oI[8], nK[8], nI[8];
            for (int i = 0; i < 8; ++i) { oK[i] = candK[row * 8 + i]; oI[i] = candI[row * 8 + i]; }
            int a = 0, b = 0;
            for (int i = 0; i < 8; ++i) {
                if (oK[a] >= bK[b]) { nK[i] = oK[a]; nI[i] = oI[a]; ++a; }  // old idx lower
                else { nK[i] = bK[b]; nI[i] = bI[b]; ++b; }
            }
            for (int i = 0; i < 8; ++i) { candK[row * 8 + i] = nK[i]; candI[row * 8 + i] = nI[i]; }
        }
    }
}

// ---------------------------------------------------------------------------
// fp64 rescore of 8 candidates (rows cached in LDS), exact top-5, softmax,
// blend, write. One block / row.
// ---------------------------------------------------------------------------
__global__ __launch_bounds__(256)
void finalize_kernel(const float* __restrict__ emb, const float* __restrict__ voc,
                     const double* __restrict__ invA, const double* __restrict__ invB,
                     const int* __restrict__ candI, float* __restrict__ out)
{
    constexpr int D = 2048;
    __shared__ float rows8[8][D];    // 64 KB
    __shared__ float erow[D];        // 8 KB
    __shared__ double wred[4][8];
    __shared__ double s8[8];
    __shared__ int i8[8];
    __shared__ float w5[5];
    __shared__ int slot5[5];
    const int row = blockIdx.x;
    const int t = threadIdx.x;
    const int lane = t & 63;
    const int wave = t >> 6;

    if (t < 8) i8[t] = candI[row * 8 + t];
    __syncthreads();
    {
        const float4v* er = (const float4v*)(emb + (size_t)row * D);
        float4v* ed = (float4v*)erow;
        ed[t] = er[t];
        ed[t + 256] = er[t + 256];
#pragma unroll
        for (int k = 0; k < 8; ++k) {
            const float4v* src = (const float4v*)(voc + (size_t)i8[k] * D);
            float4v* dst = (float4v*)rows8[k];
            dst[t] = src[t];
            dst[t + 256] = src[t + 256];
        }
    }
    __syncthreads();

    double part[8] = {0, 0, 0, 0, 0, 0, 0, 0};
#pragma unroll
    for (int i = 0; i < 8; ++i) {
        int d = t + i * 256;
        double e = (double)erow[d];
#pragma unroll
        for (int k = 0; k < 8; ++k) part[k] += e * (double)rows8[k][d];
    }
#pragma unroll
    for (int k = 0; k < 8; ++k) {
#pragma unroll
        for (int off = 32; off > 0; off >>= 1) part[k] += __shfl_down(part[k], off);
        if (lane == 0) wred[wave][k] = part[k];
    }
    __syncthreads();
    if (t < 8) {
        double sum = wred[0][t] + wred[1][t] + wred[2][t] + wred[3][t];
        s8[t] = sum * invA[row] * invB[i8[t]];
    }
    __syncthreads();
    if (t == 0) {
        int ord[8] = {0, 1, 2, 3, 4, 5, 6, 7};
        for (int a = 0; a < 5; ++a) {
            int best = a;
            for (int b = a + 1; b < 8; ++b) {
                if (s8[ord[b]] > s8[ord[best]] ||
                    (s8[ord[b]] == s8[ord[best]] && i8[ord[b]] < i8[ord[best]]))
                    best = b;
            }
            int tmp = ord[a]; ord[a] = ord[best]; ord[best] = tmp;
        }
        double m = s8[ord[0]];
        double e[5], sum = 0.0;
        for (int k = 0; k < 5; ++k) { e[k] = exp((s8[ord[k]] - m) * 10.0); sum += e[k]; }
        for (int k = 0; k < 5; ++k) {
            w5[k] = (float)(e[k] / sum);
            slot5[k] = ord[k];
        }
    }
    __syncthreads();
    float q0 = w5[0], q1 = w5[1], q2 = w5[2], q3 = w5[3], q4 = w5[4];
    int s0 = slot5[0], s1 = slot5[1], s2 = slot5[2], s3 = slot5[3], s4 = slot5[4];
    float* orow = out + (size_t)row * D;
#pragma unroll
    for (int i = 0; i < 8; ++i) {
        int d = t + i * 256;
        float p = q0 * rows8[s0][d] + q1 * rows8[s1][d] + q2 * rows8[s2][d] +
                  q3 * rows8[s3][d] + q4 * rows8[s4][d];
        orow[d] = 0.5f * erow[d] + 0.5f * p;
    }
}

// ---------------------------------------------------------------------------
extern "C" void kernel_launch(void* const* d_in, const int* in_sizes, int n_in,
                              void* d_out, int out_size, void* d_ws, size_t ws_size,
                              hipStream_t stream)
{
    (void)in_sizes; (void)n_in; (void)out_size; (void)ws_size;
    constexpr int N = 8192, V = 32000;
    constexpr int CHUNK = 1536;              // 12 x 128; last chunk = 1280
    constexpr int NCHUNK = 21;               // 20*1536 + 1280 = 32000
    const float* emb = (const float*)d_in[0];
    const float* voc = (const float*)d_in[1];
    float* out = (float*)d_out;
    char* ws = (char*)d_ws;

    // d_ws layout — TOTAL 973,824 bytes (<1 MB, proven safe):
    double* invA  = (double*)(ws);           // 65,536
    double* invB  = (double*)(ws + 65536);   // 256,000
    float*  invBf = (float*)(ws + 321536);   // 128,000
    int*    candK = (int*)(ws + 449536);     // 262,144
    int*    candI = (int*)(ws + 711680);     // 262,144

    // d_out (67,108,864 B) as scratch until finalize overwrites it:
    //   Abf      u16[8192*2048]   @ 0           (33,554,432)
    //   simsU16  u16[8192*1536]   @ 33,554,432  (25,165,824)
    //   BbfChunk u16[1536*2048]   @ 58,720,256  ( 6,291,456)  -> total 65,011,712
    u16* Abf  = (u16*)d_out;
    u16* sims = (u16*)((char*)d_out + 33554432);
    u16* Bbf  = (u16*)((char*)d_out + 58720256);

    rownorm_cast<<<N, 256, 0, stream>>>(emb, Abf, invA);
    rownorm_only<<<V, 256, 0, stream>>>(voc, invB, invBf);
    precast_rows<<<CHUNK, 256, 0, stream>>>(voc, invBf, Bbf, 0);

    for (int c = 0; c < NCHUNK; ++c) {
        int colBase = c * CHUNK;
        int cols = (c == NCHUNK - 1) ? (V - colBase) : CHUNK;   // 1536 or 1280
        int nextBase = colBase + CHUNK;
        int nextCols = (c < NCHUNK - 1)
                           ? ((c + 1 == NCHUNK - 1) ? (V - nextBase) : CHUNK)
                           : 0;
        int nwg = 64 * (cols / 128);         // 768 or 640, both % 8 == 0
        gemm_bt_u16<<<dim3(nwg), 256, 0, stream>>>(Abf, Bbf, sims, cols);
        top8_merge_u16<<<N / 4, 256, 0, stream>>>(sims, cols, colBase, candK, candI,
                                                  c == 0, voc, invBf, Bbf, nextBase,
                                                  nextCols);
    }

    finalize_kernel<<<N, 256, 0, stream>>>(emb, voc, invA, invB, candI, out);
}

// Round 5
// 2399.759 us; speedup vs baseline: 1.2719x; 1.2719x over previous
//
#include <hip/hip_runtime.h>

typedef unsigned short u16;
typedef __attribute__((ext_vector_type(8))) short short8;
typedef __attribute__((ext_vector_type(4))) float float4v;

typedef __attribute__((address_space(3))) unsigned int lds_u32;
typedef __attribute__((address_space(1))) unsigned int glb_u32;

__device__ __forceinline__ void gld16(const void* g, void* l) {
    __builtin_amdgcn_global_load_lds((const glb_u32*)g, (lds_u32*)l, 16, 0, 0);
}

__device__ __forceinline__ u16 f2bf(float f) {
    union { float f; unsigned u; } x;
    x.f = f;
    unsigned r = x.u + 0x7FFFu + ((x.u >> 16) & 1u);
    return (u16)(r >> 16);
}

// monotone u16 key of a similarity in [-1,1]; step 3.05e-5 (< bf16 screen noise)
__device__ __forceinline__ u16 simkey(float v) {
    int k = (int)((v + 1.0f) * 32768.0f);
    k = k < 0 ? 0 : (k > 65535 ? 65535 : k);
    return (u16)k;
}

// ---------------------------------------------------------------------------
// Per-row L2 norm + normalized bf16 cast (emb). One block / row, D=2048.
// ---------------------------------------------------------------------------
__global__ __launch_bounds__(256)
void rownorm_cast(const float* __restrict__ src, u16* __restrict__ dst,
                  double* __restrict__ invn)
{
    constexpr int D = 2048;
    __shared__ double red[256];
    __shared__ double invs;
    const int row = blockIdx.x;
    const int t = threadIdx.x;
    const float* sr = src + (size_t)row * D;
    float x[8];
    double ss = 0.0;
#pragma unroll
    for (int i = 0; i < 8; ++i) {
        x[i] = sr[t + i * 256];
        ss += (double)x[i] * (double)x[i];
    }
    red[t] = ss;
    __syncthreads();
    for (int s = 128; s > 0; s >>= 1) {
        if (t < s) red[t] += red[t + s];
        __syncthreads();
    }
    if (t == 0) {
        double n = sqrt(red[0]);
        double inv = 1.0 / fmax(n, 1e-12);
        invs = inv;
        invn[row] = inv;
    }
    __syncthreads();
    float inv = (float)invs;
    u16* dr = dst + (size_t)row * D;
#pragma unroll
    for (int i = 0; i < 8; ++i) dr[t + i * 256] = f2bf(x[i] * inv);
}

// ---------------------------------------------------------------------------
// Per-row L2 norm only (voc): writes double + float inverse norms.
// ---------------------------------------------------------------------------
__global__ __launch_bounds__(256)
void rownorm_only(const float* __restrict__ src, double* __restrict__ invn,
                  float* __restrict__ invnf)
{
    constexpr int D = 2048;
    __shared__ double red[256];
    const int row = blockIdx.x;
    const int t = threadIdx.x;
    const float* sr = src + (size_t)row * D;
    double ss = 0.0;
#pragma unroll
    for (int i = 0; i < 8; ++i) {
        float v = sr[t + i * 256];
        ss += (double)v * (double)v;
    }
    red[t] = ss;
    __syncthreads();
    for (int s = 128; s > 0; s >>= 1) {
        if (t < s) red[t] += red[t + s];
        __syncthreads();
    }
    if (t == 0) {
        double n = sqrt(red[0]);
        double inv = 1.0 / fmax(n, 1e-12);
        invn[row] = inv;
        invnf[row] = (float)inv;
    }
}

// ---------------------------------------------------------------------------
// Precast a block of vocab rows to normalized bf16 (chunk-local layout).
// ---------------------------------------------------------------------------
__global__ __launch_bounds__(256)
void precast_rows(const float* __restrict__ Bf, const float* __restrict__ invBf,
                  u16* __restrict__ Bbf, int colBase)
{
    const int t = threadIdx.x;
    const int v = colBase + blockIdx.x;
    float s = invBf[v];
    const float* src = Bf + (size_t)v * 2048 + t * 8;
    float4v x0 = *(const float4v*)src;
    float4v x1 = *(const float4v*)(src + 4);
    short8 pk;
    pk[0] = (short)f2bf(x0[0] * s); pk[1] = (short)f2bf(x0[1] * s);
    pk[2] = (short)f2bf(x0[2] * s); pk[3] = (short)f2bf(x0[3] * s);
    pk[4] = (short)f2bf(x1[0] * s); pk[5] = (short)f2bf(x1[1] * s);
    pk[6] = (short)f2bf(x1[2] * s); pk[7] = (short)f2bf(x1[3] * s);
    *(short8*)(Bbf + (size_t)blockIdx.x * 2048 + t * 8) = pk;
}

// ---------------------------------------------------------------------------
// 256x256 bf16 GEMM, 8 waves (2Mx4N), BK=64, double-buffered LDS (128 KB),
// counted-vmcnt pipeline (T3/T4): stage K-tile t+2 after the read-done
// barrier, wait only vmcnt(8) (tile t+1's loads) so tile t+2's 8 loads stay
// in flight across the barrier. XOR bank-swizzle (T2): 16B slot s of row r
// stored at s^(r&7), applied on the GLOBAL source address (LDS dest stays
// linear, required by global_load_lds) and on the ds_read address.
// sched_barrier(0) after EVERY s_barrier: raw s_barrier is not a compiler
// fence; without it LLVM may hoist next-iteration ds_reads above the
// buffer-ready barrier (cross-wave race, rule #18/#21 discipline).
// Per-wave output 128x64, acc[8][4]. Output u16 keys.
// ---------------------------------------------------------------------------
__global__ __launch_bounds__(512, 2)
void gemm256_bt_u16(const u16* __restrict__ A, const u16* __restrict__ B,
                    u16* __restrict__ Csim, int ldc)
{
    constexpr int Kdim = 2048;
    constexpr int NT = Kdim / 64;            // 32 K-tiles
    __shared__ __align__(16) u16 As[2][256 * 64];   // 64 KB
    __shared__ __align__(16) u16 Bs[2][256 * 64];   // 64 KB
    const int tid = threadIdx.x;
    const int lane = tid & 63;
    const int wave = tid >> 6;
    const int bx = blockIdx.x & 31;          // grid is 32 * nby blocks
    const int by = blockIdx.x >> 5;
    const int rowTile = bx * 256;
    const int colTile = by * 256;
    const u16* Ab = A + (size_t)rowTile * Kdim;
    const u16* Bb = B + (size_t)colTile * Kdim;

    const int wr = (wave >> 2) * 128;        // wave row offset (0,128)
    const int wc = (wave & 3) * 64;          // wave col offset (0..192)
    const int lr = lane & 15;
    const int lq = lane >> 4;

    float4v acc[8][4];
#pragma unroll
    for (int i = 0; i < 8; ++i)
#pragma unroll
        for (int j = 0; j < 4; ++j) acc[i][j] = (float4v){0.f, 0.f, 0.f, 0.f};

    // stage K-tile t into buffer b: 2048 16B-chunks per operand, 4/thread.
    // chunk c -> row r=c>>3, slot s=c&7; LDS linear, global pre-swizzled.
    auto stage = [&](int t, int b) {
        int k0 = t * 64;
#pragma unroll
        for (int i = 0; i < 4; ++i) {
            int c = i * 512 + tid;
            int r = c >> 3, s = c & 7;
            gld16(Ab + (size_t)r * Kdim + k0 + ((s ^ (r & 7)) * 8), &As[b][c * 8]);
        }
#pragma unroll
        for (int i = 0; i < 4; ++i) {
            int c = i * 512 + tid;
            int r = c >> 3, s = c & 7;
            gld16(Bb + (size_t)r * Kdim + k0 + ((s ^ (r & 7)) * 8), &Bs[b][c * 8]);
        }
    };

    stage(0, 0);                             // 8 loads/wave in flight
    stage(1, 1);                             // 16 in flight
    asm volatile("s_waitcnt vmcnt(8)" ::: "memory");   // tile0 (mine) landed
    __builtin_amdgcn_sched_barrier(0);
    __builtin_amdgcn_s_barrier();                      // tile0 (everyone) landed
    __builtin_amdgcn_sched_barrier(0);

    int cur = 0;
    for (int t = 0; t < NT; ++t) {
#pragma unroll
        for (int ks = 0; ks < 2; ++ks) {
            short8 af[8], bfr[4];
#pragma unroll
            for (int mi = 0; mi < 8; ++mi) {
                int r = wr + mi * 16 + lr;
                int s = (ks * 4 + lq) ^ (lr & 7);
                af[mi] = *(const short8*)&As[cur][r * 64 + s * 8];
            }
#pragma unroll
            for (int ni = 0; ni < 4; ++ni) {
                int r = wc + ni * 16 + lr;
                int s = (ks * 4 + lq) ^ (lr & 7);
                bfr[ni] = *(const short8*)&Bs[cur][r * 64 + s * 8];
            }
#pragma unroll
            for (int mi = 0; mi < 8; ++mi)
#pragma unroll
                for (int ni = 0; ni < 4; ++ni)
                    acc[mi][ni] = __builtin_amdgcn_mfma_f32_16x16x32_bf16(
                        af[mi], bfr[ni], acc[mi][ni], 0, 0, 0);
        }
        // all my reads of buf[cur] complete -> signal, then overwrite it
        asm volatile("s_waitcnt lgkmcnt(0)" ::: "memory");
        __builtin_amdgcn_sched_barrier(0);
        __builtin_amdgcn_s_barrier();        // everyone done reading buf[cur]
        __builtin_amdgcn_sched_barrier(0);
        if (t + 2 < NT) {
            stage(t + 2, cur);               // 8 new loads; 16 now in flight
            asm volatile("s_waitcnt vmcnt(8)" ::: "memory");  // t+1's landed
        } else if (t + 1 < NT) {
            asm volatile("s_waitcnt vmcnt(0)" ::: "memory");  // drain tail
        }
        __builtin_amdgcn_sched_barrier(0);
        __builtin_amdgcn_s_barrier();        // buf[cur^1] visible to all
        __builtin_amdgcn_sched_barrier(0);   // pin next ds_reads below barrier
        cur ^= 1;
    }

    // C/D layout: col = lane&15, row = (lane>>4)*4 + reg
#pragma unroll
    for (int mi = 0; mi < 8; ++mi) {
#pragma unroll
        for (int r = 0; r < 4; ++r) {
            int row = rowTile + wr + mi * 16 + lq * 4 + r;
            u16* crow = Csim + (size_t)row * ldc + colTile + wc + lr;
#pragma unroll
            for (int ni = 0; ni < 4; ++ni) crow[ni * 16] = simkey(acc[mi][ni][r]);
        }
    }
}

// ---------------------------------------------------------------------------
// Per-row top-8: one wave per row (4 rows/block, zero barriers, zero LDS).
// Packed key|idx int -> single __shfl_xor butterfly per pass. Fold: blocks
// 0..nextCols-1 also stage next chunk's bf16 B rows. grid = N/4.
// ---------------------------------------------------------------------------
__global__ __launch_bounds__(256)
void top8_merge_u16(const u16* __restrict__ sims, int cols, int colBase,
                    int* __restrict__ candK, int* __restrict__ candI, int isFirst,
                    const float* __restrict__ Bf, const float* __restrict__ invBf,
                    u16* __restrict__ Bbf, int nextBase, int nextCols)
{
    const int t = threadIdx.x;

    // fold: stage next chunk's normalized-bf16 B rows (uniform per block)
    if (blockIdx.x < nextCols) {
        int v = nextBase + blockIdx.x;
        float s = invBf[v];
        const float* src = Bf + (size_t)v * 2048 + t * 8;
        float4v x0 = *(const float4v*)src;
        float4v x1 = *(const float4v*)(src + 4);
        short8 pks;
        pks[0] = (short)f2bf(x0[0] * s); pks[1] = (short)f2bf(x0[1] * s);
        pks[2] = (short)f2bf(x0[2] * s); pks[3] = (short)f2bf(x0[3] * s);
        pks[4] = (short)f2bf(x1[0] * s); pks[5] = (short)f2bf(x1[1] * s);
        pks[6] = (short)f2bf(x1[2] * s); pks[7] = (short)f2bf(x1[3] * s);
        *(short8*)(Bbf + (size_t)blockIdx.x * 2048 + t * 8) = pks;
    }

    const int lane = t & 63;
    const int wave = t >> 6;
    const int row = blockIdx.x * 4 + wave;
    const u16* srow = sims + (size_t)row * cols;

    // load 24 keys/lane via 3 x short8 (16B aligned; OOB-of-row reads stay
    // inside the sims buffer and are masked to -1)
    int pk[24];
#pragma unroll
    for (int i = 0; i < 3; ++i) {
        short8 v = *(const short8*)(srow + i * 512 + lane * 8);
#pragma unroll
        for (int e = 0; e < 8; ++e) {
            int j = i * 512 + lane * 8 + e;
            int key = (int)(u16)v[e];
            pk[i * 8 + e] = (j < cols) ? ((key << 11) | (2047 - j)) : -1;
        }
    }

    int best[8];
#pragma unroll
    for (int p = 0; p < 8; ++p) {
        int bv = -1;
#pragma unroll
        for (int i = 0; i < 24; ++i) bv = pk[i] > bv ? pk[i] : bv;
#pragma unroll
        for (int off = 32; off > 0; off >>= 1) {
            int ov = __shfl_xor(bv, off);
            bv = ov > bv ? ov : bv;
        }
        best[p] = bv;                       // all lanes agree
        int cj = 2047 - (bv & 2047);        // winning column (chunk-local)
#pragma unroll
        for (int i = 0; i < 3; ++i)
#pragma unroll
            for (int e = 0; e < 8; ++e)
                if (i * 512 + lane * 8 + e == cj) pk[i * 8 + e] = -1;
    }

    if (lane == 0) {
        int bK[8], bI[8];
#pragma unroll
        for (int p = 0; p < 8; ++p) {
            bK[p] = best[p] >> 11;
            bI[p] = colBase + (2047 - (best[p] & 2047));
        }
        if (isFirst) {
            for (int i = 0; i < 8; ++i) {
                candK[row * 8 + i] = bK[i];
                candI[row * 8 + i] = bI[i];
            }
        } else {
            int oK[8], oI[8], nK[8], nI[8];
            for (int i = 0; i < 8; ++i) { oK[i] = candK[row * 8 + i]; oI[i] = candI[row * 8 + i]; }
            int a = 0, b = 0;
            for (int i = 0; i < 8; ++i) {
                if (oK[a] >= bK[b]) { nK[i] = oK[a]; nI[i] = oI[a]; ++a; }  // old idx lower
                else { nK[i] = bK[b]; nI[i] = bI[b]; ++b; }
            }
            for (int i = 0; i < 8; ++i) { candK[row * 8 + i] = nK[i]; candI[row * 8 + i] = nI[i]; }
        }
    }
}

// ---------------------------------------------------------------------------
// fp64 rescore of 8 candidates (rows cached in LDS), exact top-5, softmax,
// blend, write. One block / row.
// ---------------------------------------------------------------------------
__global__ __launch_bounds__(256)
void finalize_kernel(const float* __restrict__ emb, const float* __restrict__ voc,
                     const double* __restrict__ invA, const double* __restrict__ invB,
                     const int* __restrict__ candI, float* __restrict__ out)
{
    constexpr int D = 2048;
    __shared__ float rows8[8][D];    // 64 KB
    __shared__ float erow[D];        // 8 KB
    __shared__ double wred[4][8];
    __shared__ double s8[8];
    __shared__ int i8[8];
    __shared__ float w5[5];
    __shared__ int slot5[5];
    const int row = blockIdx.x;
    const int t = threadIdx.x;
    const int lane = t & 63;
    const int wave = t >> 6;

    if (t < 8) i8[t] = candI[row * 8 + t];
    __syncthreads();
    {
        const float4v* er = (const float4v*)(emb + (size_t)row * D);
        float4v* ed = (float4v*)erow;
        ed[t] = er[t];
        ed[t + 256] = er[t + 256];
#pragma unroll
        for (int k = 0; k < 8; ++k) {
            const float4v* src = (const float4v*)(voc + (size_t)i8[k] * D);
            float4v* dst = (float4v*)rows8[k];
            dst[t] = src[t];
            dst[t + 256] = src[t + 256];
        }
    }
    __syncthreads();

    double part[8] = {0, 0, 0, 0, 0, 0, 0, 0};
#pragma unroll
    for (int i = 0; i < 8; ++i) {
        int d = t + i * 256;
        double e = (double)erow[d];
#pragma unroll
        for (int k = 0; k < 8; ++k) part[k] += e * (double)rows8[k][d];
    }
#pragma unroll
    for (int k = 0; k < 8; ++k) {
#pragma unroll
        for (int off = 32; off > 0; off >>= 1) part[k] += __shfl_down(part[k], off);
        if (lane == 0) wred[wave][k] = part[k];
    }
    __syncthreads();
    if (t < 8) {
        double sum = wred[0][t] + wred[1][t] + wred[2][t] + wred[3][t];
        s8[t] = sum * invA[row] * invB[i8[t]];
    }
    __syncthreads();
    if (t == 0) {
        int ord[8] = {0, 1, 2, 3, 4, 5, 6, 7};
        for (int a = 0; a < 5; ++a) {
            int best = a;
            for (int b = a + 1; b < 8; ++b) {
                if (s8[ord[b]] > s8[ord[best]] ||
                    (s8[ord[b]] == s8[ord[best]] && i8[ord[b]] < i8[ord[best]]))
                    best = b;
            }
            int tmp = ord[a]; ord[a] = ord[best]; ord[best] = tmp;
        }
        double m = s8[ord[0]];
        double e[5], sum = 0.0;
        for (int k = 0; k < 5; ++k) { e[k] = exp((s8[ord[k]] - m) * 10.0); sum += e[k]; }
        for (int k = 0; k < 5; ++k) {
            w5[k] = (float)(e[k] / sum);
            slot5[k] = ord[k];
        }
    }
    __syncthreads();
    float q0 = w5[0], q1 = w5[1], q2 = w5[2], q3 = w5[3], q4 = w5[4];
    int s0 = slot5[0], s1 = slot5[1], s2 = slot5[2], s3 = slot5[3], s4 = slot5[4];
    float* orow = out + (size_t)row * D;
#pragma unroll
    for (int i = 0; i < 8; ++i) {
        int d = t + i * 256;
        float p = q0 * rows8[s0][d] + q1 * rows8[s1][d] + q2 * rows8[s2][d] +
                  q3 * rows8[s3][d] + q4 * rows8[s4][d];
        orow[d] = 0.5f * erow[d] + 0.5f * p;
    }
}

// ---------------------------------------------------------------------------
extern "C" void kernel_launch(void* const* d_in, const int* in_sizes, int n_in,
                              void* d_out, int out_size, void* d_ws, size_t ws_size,
                              hipStream_t stream)
{
    (void)in_sizes; (void)n_in; (void)out_size; (void)ws_size;
    constexpr int N = 8192, V = 32000;
    constexpr int CHUNK = 1536;              // 6 x 256; last chunk = 1280 = 5 x 256
    constexpr int NCHUNK = 21;               // 20*1536 + 1280 = 32000
    const float* emb = (const float*)d_in[0];
    const float* voc = (const float*)d_in[1];
    float* out = (float*)d_out;
    char* ws = (char*)d_ws;

    // d_ws layout — TOTAL 973,824 bytes (<1 MB, proven safe):
    double* invA  = (double*)(ws);           // 65,536
    double* invB  = (double*)(ws + 65536);   // 256,000
    float*  invBf = (float*)(ws + 321536);   // 128,000
    int*    candK = (int*)(ws + 449536);     // 262,144
    int*    candI = (int*)(ws + 711680);     // 262,144

    // d_out (67,108,864 B) as scratch until finalize overwrites it:
    //   Abf      u16[8192*2048]   @ 0           (33,554,432)
    //   simsU16  u16[8192*1536]   @ 33,554,432  (25,165,824)
    //   BbfChunk u16[1536*2048]   @ 58,720,256  ( 6,291,456)  -> total 65,011,712
    u16* Abf  = (u16*)d_out;
    u16* sims = (u16*)((char*)d_out + 33554432);
    u16* Bbf  = (u16*)((char*)d_out + 58720256);

    rownorm_cast<<<N, 256, 0, stream>>>(emb, Abf, invA);
    rownorm_only<<<V, 256, 0, stream>>>(voc, invB, invBf);
    precast_rows<<<CHUNK, 256, 0, stream>>>(voc, invBf, Bbf, 0);

    for (int c = 0; c < NCHUNK; ++c) {
        int colBase = c * CHUNK;
        int cols = (c == NCHUNK - 1) ? (V - colBase) : CHUNK;   // 1536 or 1280
        int nextBase = colBase + CHUNK;
        int nextCols = (c < NCHUNK - 1)
                           ? ((c + 1 == NCHUNK - 1) ? (V - nextBase) : CHUNK)
                           : 0;
        int nwg = 32 * (cols / 256);         // 192 or 160 blocks, all resident
        gemm256_bt_u16<<<dim3(nwg), 512, 0, stream>>>(Abf, Bbf, sims, cols);
        top8_merge_u16<<<N / 4, 256, 0, stream>>>(sims, cols, colBase, candK, candI,
                                                  c == 0, voc, invBf, Bbf, nextBase,
                                                  nextCols);
    }

    finalize_kernel<<<N, 256, 0, stream>>>(emb, voc, invA, invB, candI, out);
}

// Round 6
// 2231.447 us; speedup vs baseline: 1.3679x; 1.0754x over previous
//
#include <hip/hip_runtime.h>

typedef unsigned short u16;
typedef __attribute__((ext_vector_type(8))) short short8;
typedef __attribute__((ext_vector_type(4))) float float4v;

typedef __attribute__((address_space(3))) unsigned int lds_u32;
typedef __attribute__((address_space(1))) unsigned int glb_u32;

__device__ __forceinline__ void gld16(const void* g, void* l) {
    __builtin_amdgcn_global_load_lds((const glb_u32*)g, (lds_u32*)l, 16, 0, 0);
}

__device__ __forceinline__ u16 f2bf(float f) {
    union { float f; unsigned u; } x;
    x.f = f;
    unsigned r = x.u + 0x7FFFu + ((x.u >> 16) & 1u);
    return (u16)(r >> 16);
}

// monotone u16 key of a similarity in [-1,1]; step 3.05e-5 (< bf16 screen noise)
__device__ __forceinline__ u16 simkey(float v) {
    int k = (int)((v + 1.0f) * 32768.0f);
    k = k < 0 ? 0 : (k > 65535 ? 65535 : k);
    return (u16)k;
}

// ---------------------------------------------------------------------------
// Per-row L2 norm + normalized bf16 cast (emb). One block / row, D=2048.
// ---------------------------------------------------------------------------
__global__ __launch_bounds__(256)
void rownorm_cast(const float* __restrict__ src, u16* __restrict__ dst,
                  double* __restrict__ invn)
{
    constexpr int D = 2048;
    __shared__ double red[256];
    __shared__ double invs;
    const int row = blockIdx.x;
    const int t = threadIdx.x;
    const float* sr = src + (size_t)row * D;
    float x[8];
    double ss = 0.0;
#pragma unroll
    for (int i = 0; i < 8; ++i) {
        x[i] = sr[t + i * 256];
        ss += (double)x[i] * (double)x[i];
    }
    red[t] = ss;
    __syncthreads();
    for (int s = 128; s > 0; s >>= 1) {
        if (t < s) red[t] += red[t + s];
        __syncthreads();
    }
    if (t == 0) {
        double n = sqrt(red[0]);
        double inv = 1.0 / fmax(n, 1e-12);
        invs = inv;
        invn[row] = inv;
    }
    __syncthreads();
    float inv = (float)invs;
    u16* dr = dst + (size_t)row * D;
#pragma unroll
    for (int i = 0; i < 8; ++i) dr[t + i * 256] = f2bf(x[i] * inv);
}

// ---------------------------------------------------------------------------
// Per-row L2 norm only (voc): writes double + float inverse norms.
// ---------------------------------------------------------------------------
__global__ __launch_bounds__(256)
void rownorm_only(const float* __restrict__ src, double* __restrict__ invn,
                  float* __restrict__ invnf)
{
    constexpr int D = 2048;
    __shared__ double red[256];
    const int row = blockIdx.x;
    const int t = threadIdx.x;
    const float* sr = src + (size_t)row * D;
    double ss = 0.0;
#pragma unroll
    for (int i = 0; i < 8; ++i) {
        float v = sr[t + i * 256];
        ss += (double)v * (double)v;
    }
    red[t] = ss;
    __syncthreads();
    for (int s = 128; s > 0; s >>= 1) {
        if (t < s) red[t] += red[t + s];
        __syncthreads();
    }
    if (t == 0) {
        double n = sqrt(red[0]);
        double inv = 1.0 / fmax(n, 1e-12);
        invn[row] = inv;
        invnf[row] = (float)inv;
    }
}

// ---------------------------------------------------------------------------
// Precast a block of vocab rows to normalized bf16 (chunk-local layout).
// ---------------------------------------------------------------------------
__global__ __launch_bounds__(256)
void precast_rows(const float* __restrict__ Bf, const float* __restrict__ invBf,
                  u16* __restrict__ Bbf, int colBase)
{
    const int t = threadIdx.x;
    const int v = colBase + blockIdx.x;
    float s = invBf[v];
    const float* src = Bf + (size_t)v * 2048 + t * 8;
    float4v x0 = *(const float4v*)src;
    float4v x1 = *(const float4v*)(src + 4);
    short8 pk;
    pk[0] = (short)f2bf(x0[0] * s); pk[1] = (short)f2bf(x0[1] * s);
    pk[2] = (short)f2bf(x0[2] * s); pk[3] = (short)f2bf(x0[3] * s);
    pk[4] = (short)f2bf(x1[0] * s); pk[5] = (short)f2bf(x1[1] * s);
    pk[6] = (short)f2bf(x1[2] * s); pk[7] = (short)f2bf(x1[3] * s);
    *(short8*)(Bbf + (size_t)blockIdx.x * 2048 + t * 8) = pk;
}

// ---------------------------------------------------------------------------
// 256x192 bf16 GEMM, 8 waves (2Mx4N), BK=64, double-buffered LDS (112 KB),
// counted-vmcnt pipeline (T3/T4). BN=192 so the chunk grid is 32x8 = 256
// blocks = exactly one per CU (R5's BN=256 gave 192 blocks -> 25% of CUs
// idle). Per-wave output 128x48, acc[8][3]; stage = 7 gld16/lane -> steady
// state waits vmcnt(7) (one stage in flight). XOR bank-swizzle (T2) applied
// global-side + ds_read-side as before; sched_barrier(0) after every
// s_barrier (rule #18/#21 discipline). Output u16 keys, ldc = 1536 always
// (last chunk padded; top8's j<cols mask discards pad columns).
// ---------------------------------------------------------------------------
__global__ __launch_bounds__(512, 2)
void gemm256_bt_u16(const u16* __restrict__ A, const u16* __restrict__ B,
                    u16* __restrict__ Csim, int ldc)
{
    constexpr int Kdim = 2048;
    constexpr int NT = Kdim / 64;            // 32 K-tiles
    __shared__ __align__(16) u16 As[2][256 * 64];   // 64 KB
    __shared__ __align__(16) u16 Bs[2][192 * 64];   // 48 KB
    const int tid = threadIdx.x;
    const int lane = tid & 63;
    const int wave = tid >> 6;
    const int bx = blockIdx.x & 31;          // 32 row tiles
    const int by = blockIdx.x >> 5;          // 8 col tiles
    const int rowTile = bx * 256;
    const int colTile = by * 192;
    const u16* Ab = A + (size_t)rowTile * Kdim;
    const u16* Bb = B + (size_t)colTile * Kdim;

    const int wr = (wave >> 2) * 128;        // wave row offset (0,128)
    const int wc = (wave & 3) * 48;          // wave col offset (0,48,96,144)
    const int lr = lane & 15;
    const int lq = lane >> 4;

    float4v acc[8][3];
#pragma unroll
    for (int i = 0; i < 8; ++i)
#pragma unroll
        for (int j = 0; j < 3; ++j) acc[i][j] = (float4v){0.f, 0.f, 0.f, 0.f};

    // stage K-tile t into buffer b. A: 2048 16B-chunks (4/thread);
    // B: 1536 16B-chunks (3/thread). chunk c -> row r=c>>3, slot s=c&7;
    // LDS linear, global pre-swizzled (s ^ (r&7)).
    auto stage = [&](int t, int b) {
        int k0 = t * 64;
#pragma unroll
        for (int i = 0; i < 4; ++i) {
            int c = i * 512 + tid;
            int r = c >> 3, s = c & 7;
            gld16(Ab + (size_t)r * Kdim + k0 + ((s ^ (r & 7)) * 8), &As[b][c * 8]);
        }
#pragma unroll
        for (int i = 0; i < 3; ++i) {
            int c = i * 512 + tid;
            int r = c >> 3, s = c & 7;
            gld16(Bb + (size_t)r * Kdim + k0 + ((s ^ (r & 7)) * 8), &Bs[b][c * 8]);
        }
    };

    stage(0, 0);                             // 7 loads/lane in flight
    stage(1, 1);                             // 14 in flight
    asm volatile("s_waitcnt vmcnt(7)" ::: "memory");   // tile0 (mine) landed
    __builtin_amdgcn_sched_barrier(0);
    __builtin_amdgcn_s_barrier();                      // tile0 (everyone) landed
    __builtin_amdgcn_sched_barrier(0);

    int cur = 0;
    for (int t = 0; t < NT; ++t) {
#pragma unroll
        for (int ks = 0; ks < 2; ++ks) {
            short8 af[8], bfr[3];
#pragma unroll
            for (int mi = 0; mi < 8; ++mi) {
                int r = wr + mi * 16 + lr;
                int s = (ks * 4 + lq) ^ (lr & 7);
                af[mi] = *(const short8*)&As[cur][r * 64 + s * 8];
            }
#pragma unroll
            for (int ni = 0; ni < 3; ++ni) {
                int r = wc + ni * 16 + lr;
                int s = (ks * 4 + lq) ^ (lr & 7);
                bfr[ni] = *(const short8*)&Bs[cur][r * 64 + s * 8];
            }
#pragma unroll
            for (int mi = 0; mi < 8; ++mi)
#pragma unroll
                for (int ni = 0; ni < 3; ++ni)
                    acc[mi][ni] = __builtin_amdgcn_mfma_f32_16x16x32_bf16(
                        af[mi], bfr[ni], acc[mi][ni], 0, 0, 0);
        }
        // all my reads of buf[cur] complete -> signal, then overwrite it
        asm volatile("s_waitcnt lgkmcnt(0)" ::: "memory");
        __builtin_amdgcn_sched_barrier(0);
        __builtin_amdgcn_s_barrier();        // everyone done reading buf[cur]
        __builtin_amdgcn_sched_barrier(0);
        if (t + 2 < NT) {
            stage(t + 2, cur);               // 7 new loads; 14 now in flight
            asm volatile("s_waitcnt vmcnt(7)" ::: "memory");  // t+1's landed
        } else if (t + 1 < NT) {
            asm volatile("s_waitcnt vmcnt(0)" ::: "memory");  // drain tail
        }
        __builtin_amdgcn_sched_barrier(0);
        __builtin_amdgcn_s_barrier();        // buf[cur^1] visible to all
        __builtin_amdgcn_sched_barrier(0);   // pin next ds_reads below barrier
        cur ^= 1;
    }

    // C/D layout: col = lane&15, row = (lane>>4)*4 + reg
#pragma unroll
    for (int mi = 0; mi < 8; ++mi) {
#pragma unroll
        for (int r = 0; r < 4; ++r) {
            int row = rowTile + wr + mi * 16 + lq * 4 + r;
            u16* crow = Csim + (size_t)row * ldc + colTile + wc + lr;
#pragma unroll
            for (int ni = 0; ni < 3; ++ni) crow[ni * 16] = simkey(acc[mi][ni][r]);
        }
    }
}

// ---------------------------------------------------------------------------
// Per-row top-8: one wave per row (4 rows/block, zero barriers, zero LDS).
// Packed key|idx int -> single __shfl_xor butterfly per pass. Row stride is
// ldc (1536); only j < cols participate (pad columns masked). Fold: blocks
// 0..nextCols-1 also stage next chunk's bf16 B rows. grid = N/4.
// ---------------------------------------------------------------------------
__global__ __launch_bounds__(256)
void top8_merge_u16(const u16* __restrict__ sims, int ldc, int cols, int colBase,
                    int* __restrict__ candK, int* __restrict__ candI, int isFirst,
                    const float* __restrict__ Bf, const float* __restrict__ invBf,
                    u16* __restrict__ Bbf, int nextBase, int nextCols)
{
    const int t = threadIdx.x;

    // fold: stage next chunk's normalized-bf16 B rows (uniform per block)
    if (blockIdx.x < nextCols) {
        int v = nextBase + blockIdx.x;
        float s = invBf[v];
        const float* src = Bf + (size_t)v * 2048 + t * 8;
        float4v x0 = *(const float4v*)src;
        float4v x1 = *(const float4v*)(src + 4);
        short8 pks;
        pks[0] = (short)f2bf(x0[0] * s); pks[1] = (short)f2bf(x0[1] * s);
        pks[2] = (short)f2bf(x0[2] * s); pks[3] = (short)f2bf(x0[3] * s);
        pks[4] = (short)f2bf(x1[0] * s); pks[5] = (short)f2bf(x1[1] * s);
        pks[6] = (short)f2bf(x1[2] * s); pks[7] = (short)f2bf(x1[3] * s);
        *(short8*)(Bbf + (size_t)blockIdx.x * 2048 + t * 8) = pks;
    }

    const int lane = t & 63;
    const int wave = t >> 6;
    const int row = blockIdx.x * 4 + wave;
    const u16* srow = sims + (size_t)row * ldc;

    // load 24 keys/lane via 3 x short8 (16B aligned); mask j >= cols to -1
    int pk[24];
#pragma unroll
    for (int i = 0; i < 3; ++i) {
        short8 v = *(const short8*)(srow + i * 512 + lane * 8);
#pragma unroll
        for (int e = 0; e < 8; ++e) {
            int j = i * 512 + lane * 8 + e;
            int key = (int)(u16)v[e];
            pk[i * 8 + e] = (j < cols) ? ((key << 11) | (2047 - j)) : -1;
        }
    }

    int best[8];
#pragma unroll
    for (int p = 0; p < 8; ++p) {
        int bv = -1;
#pragma unroll
        for (int i = 0; i < 24; ++i) bv = pk[i] > bv ? pk[i] : bv;
#pragma unroll
        for (int off = 32; off > 0; off >>= 1) {
            int ov = __shfl_xor(bv, off);
            bv = ov > bv ? ov : bv;
        }
        best[p] = bv;                       // all lanes agree
        int cj = 2047 - (bv & 2047);        // winning column (chunk-local)
#pragma unroll
        for (int i = 0; i < 3; ++i)
#pragma unroll
            for (int e = 0; e < 8; ++e)
                if (i * 512 + lane * 8 + e == cj) pk[i * 8 + e] = -1;
    }

    if (lane == 0) {
        int bK[8], bI[8];
#pragma unroll
        for (int p = 0; p < 8; ++p) {
            bK[p] = best[p] >> 11;
            bI[p] = colBase + (2047 - (best[p] & 2047));
        }
        if (isFirst) {
            for (int i = 0; i < 8; ++i) {
                candK[row * 8 + i] = bK[i];
                candI[row * 8 + i] = bI[i];
            }
        } else {
            int oK[8], oI[8], nK[8], nI[8];
            for (int i = 0; i < 8; ++i) { oK[i] = candK[row * 8 + i]; oI[i] = candI[row * 8 + i]; }
            int a = 0, b = 0;
            for (int i = 0; i < 8; ++i) {
                if (oK[a] >= bK[b]) { nK[i] = oK[a]; nI[i] = oI[a]; ++a; }  // old idx lower
                else { nK[i] = bK[b]; nI[i] = bI[b]; ++b; }
            }
            for (int i = 0; i < 8; ++i) { candK[row * 8 + i] = nK[i]; candI[row * 8 + i] = nI[i]; }
        }
    }
}

// ---------------------------------------------------------------------------
// fp64 rescore of 8 candidates (rows cached in LDS), exact top-5, softmax,
// blend, write. One block / row.
// ---------------------------------------------------------------------------
__global__ __launch_bounds__(256)
void finalize_kernel(const float* __restrict__ emb, const float* __restrict__ voc,
                     const double* __restrict__ invA, const double* __restrict__ invB,
                     const int* __restrict__ candI, float* __restrict__ out)
{
    constexpr int D = 2048;
    __shared__ float rows8[8][D];    // 64 KB
    __shared__ float erow[D];        // 8 KB
    __shared__ double wred[4][8];
    __shared__ double s8[8];
    __shared__ int i8[8];
    __shared__ float w5[5];
    __shared__ int slot5[5];
    const int row = blockIdx.x;
    const int t = threadIdx.x;
    const int lane = t & 63;
    const int wave = t >> 6;

    if (t < 8) i8[t] = candI[row * 8 + t];
    __syncthreads();
    {
        const float4v* er = (const float4v*)(emb + (size_t)row * D);
        float4v* ed = (float4v*)erow;
        ed[t] = er[t];
        ed[t + 256] = er[t + 256];
#pragma unroll
        for (int k = 0; k < 8; ++k) {
            const float4v* src = (const float4v*)(voc + (size_t)i8[k] * D);
            float4v* dst = (float4v*)rows8[k];
            dst[t] = src[t];
            dst[t + 256] = src[t + 256];
        }
    }
    __syncthreads();

    double part[8] = {0, 0, 0, 0, 0, 0, 0, 0};
#pragma unroll
    for (int i = 0; i < 8; ++i) {
        int d = t + i * 256;
        double e = (double)erow[d];
#pragma unroll
        for (int k = 0; k < 8; ++k) part[k] += e * (double)rows8[k][d];
    }
#pragma unroll
    for (int k = 0; k < 8; ++k) {
#pragma unroll
        for (int off = 32; off > 0; off >>= 1) part[k] += __shfl_down(part[k], off);
        if (lane == 0) wred[wave][k] = part[k];
    }
    __syncthreads();
    if (t < 8) {
        double sum = wred[0][t] + wred[1][t] + wred[2][t] + wred[3][t];
        s8[t] = sum * invA[row] * invB[i8[t]];
    }
    __syncthreads();
    if (t == 0) {
        int ord[8] = {0, 1, 2, 3, 4, 5, 6, 7};
        for (int a = 0; a < 5; ++a) {
            int best = a;
            for (int b = a + 1; b < 8; ++b) {
                if (s8[ord[b]] > s8[ord[best]] ||
                    (s8[ord[b]] == s8[ord[best]] && i8[ord[b]] < i8[ord[best]]))
                    best = b;
            }
            int tmp = ord[a]; ord[a] = ord[best]; ord[best] = tmp;
        }
        double m = s8[ord[0]];
        double e[5], sum = 0.0;
        for (int k = 0; k < 5; ++k) { e[k] = exp((s8[ord[k]] - m) * 10.0); sum += e[k]; }
        for (int k = 0; k < 5; ++k) {
            w5[k] = (float)(e[k] / sum);
            slot5[k] = ord[k];
        }
    }
    __syncthreads();
    float q0 = w5[0], q1 = w5[1], q2 = w5[2], q3 = w5[3], q4 = w5[4];
    int s0 = slot5[0], s1 = slot5[1], s2 = slot5[2], s3 = slot5[3], s4 = slot5[4];
    float* orow = out + (size_t)row * D;
#pragma unroll
    for (int i = 0; i < 8; ++i) {
        int d = t + i * 256;
        float p = q0 * rows8[s0][d] + q1 * rows8[s1][d] + q2 * rows8[s2][d] +
                  q3 * rows8[s3][d] + q4 * rows8[s4][d];
        orow[d] = 0.5f * erow[d] + 0.5f * p;
    }
}

// ---------------------------------------------------------------------------
extern "C" void kernel_launch(void* const* d_in, const int* in_sizes, int n_in,
                              void* d_out, int out_size, void* d_ws, size_t ws_size,
                              hipStream_t stream)
{
    (void)in_sizes; (void)n_in; (void)out_size; (void)ws_size;
    constexpr int N = 8192, V = 32000;
    constexpr int CHUNK = 1536;              // 8 x 192; last chunk 1280 padded to 1536
    constexpr int NCHUNK = 21;               // 20*1536 + 1280 = 32000
    const float* emb = (const float*)d_in[0];
    const float* voc = (const float*)d_in[1];
    float* out = (float*)d_out;
    char* ws = (char*)d_ws;

    // d_ws layout — TOTAL 973,824 bytes (<1 MB, proven safe):
    double* invA  = (double*)(ws);           // 65,536
    double* invB  = (double*)(ws + 65536);   // 256,000
    float*  invBf = (float*)(ws + 321536);   // 128,000
    int*    candK = (int*)(ws + 449536);     // 262,144
    int*    candI = (int*)(ws + 711680);     // 262,144

    // d_out (67,108,864 B) as scratch until finalize overwrites it:
    //   Abf      u16[8192*2048]   @ 0           (33,554,432)
    //   simsU16  u16[8192*1536]   @ 33,554,432  (25,165,824)
    //   BbfChunk u16[1536*2048]   @ 58,720,256  ( 6,291,456)  -> total 65,011,712
    u16* Abf  = (u16*)d_out;
    u16* sims = (u16*)((char*)d_out + 33554432);
    u16* Bbf  = (u16*)((char*)d_out + 58720256);

    rownorm_cast<<<N, 256, 0, stream>>>(emb, Abf, invA);
    rownorm_only<<<V, 256, 0, stream>>>(voc, invB, invBf);
    precast_rows<<<CHUNK, 256, 0, stream>>>(voc, invBf, Bbf, 0);

    for (int c = 0; c < NCHUNK; ++c) {
        int colBase = c * CHUNK;
        int cols = (c == NCHUNK - 1) ? (V - colBase) : CHUNK;   // 1536 or 1280
        int nextBase = colBase + CHUNK;
        int nextCols = (c < NCHUNK - 1)
                           ? ((c + 1 == NCHUNK - 1) ? (V - nextBase) : CHUNK)
                           : 0;
        // GEMM always computes the full padded 1536 cols: 32 x 8 = 256 blocks
        // (exactly one per CU). Pad B rows are stale-but-valid; top8 masks.
        gemm256_bt_u16<<<dim3(256), 512, 0, stream>>>(Abf, Bbf, sims, CHUNK);
        top8_merge_u16<<<N / 4, 256, 0, stream>>>(sims, CHUNK, cols, colBase,
                                                  candK, candI, c == 0, voc,
                                                  invBf, Bbf, nextBase, nextCols);
    }

    finalize_kernel<<<N, 256, 0, stream>>>(emb, voc, invA, invB, candI, out);
}